// Round 11
// baseline (1016.512 us; speedup 1.0000x reference)
//
#include <hip/hip_runtime.h>
#include <hip/hip_bf16.h>
#include <cstddef>

#define NN 200000   // nodes
#define NE 400000   // edges
#define DD 128      // embed dim
#define NL 5        // layers
#define NG 1000     // graphs
#define BOND_V 5
#define BM 16             // rows per fused block
#define NBLK (NN / BM)    // 12500
#define MAXD 16           // padded edge slots per row (deg>16 -> serial fallback)
#define PCH 200           // pool rows per block (1000 blocks)
#define NB_SCAN 200
#define CH 1000
#define SB 125            // k_stats blocks (500 regressed r9: atomic contention)
#define EPS 1e-5f
#define XS 136            // Xh/Xl row stride (shorts), 272B = 17*16 -> b128-aligned

typedef __bf16 bf16x8 __attribute__((ext_vector_type(8)));
typedef float floatx4 __attribute__((ext_vector_type(4)));

__device__ __forceinline__ unsigned short f2bf(float f) {
    unsigned int u = __float_as_uint(f);
    u = (u + 0x7fffu + ((u >> 16) & 1u)) >> 16;
    return (unsigned short)u;
}
__device__ __forceinline__ float bf2f(unsigned short s) {
    return __uint_as_float(((unsigned int)s) << 16);
}
__device__ __forceinline__ float4 bf4_to_f4(uint2 v) {
    float4 o;
    o.x = __uint_as_float(v.x << 16);
    o.y = __uint_as_float(v.x & 0xffff0000u);
    o.z = __uint_as_float(v.y << 16);
    o.w = __uint_as_float(v.y & 0xffff0000u);
    return o;
}
__device__ __forceinline__ float4 actv4(float4 h, float4 sc, float4 sh) {
    float4 o;
    o.x = fmaxf(0.f, h.x * sc.x + sh.x);
    o.y = fmaxf(0.f, h.y * sc.y + sh.y);
    o.z = fmaxf(0.f, h.z * sc.z + sh.z);
    o.w = fmaxf(0.f, h.w * sc.w + sh.w);
    return o;
}

// ---------------- merged setup: degree cnt, graph cnt, W split ----------------
__global__ void k_setup1(const int* __restrict__ dst, int* __restrict__ cnt,
                         const int* __restrict__ n2g, float* __restrict__ gcnt,
                         const float* __restrict__ W, unsigned short* __restrict__ Wht,
                         unsigned short* __restrict__ Wlt) {
    int e = blockIdx.x * blockDim.x + threadIdx.x;
    if (e < NE) atomicAdd(&cnt[dst[e]], 1);
    if (e < NN) atomicAdd(&gcnt[n2g[e]], 1.0f);
    if (e < NL * DD * DD) {
        int l = e / (DD * DD), rem = e % (DD * DD);
        int k = rem / DD, n = rem % DD;
        float v = W[e];
        unsigned short hb = f2bf(v);
        unsigned short lb = f2bf(v - bf2f(hb));
        size_t o = (size_t)l * DD * DD + (size_t)n * DD + k;
        Wht[o] = hb; Wlt[o] = lb;
    }
}

// ---------------- CSR build ----------------
__global__ void k_scan1(const int* __restrict__ cnt, int* __restrict__ bsum) {
    __shared__ int sh[256];
    int b = blockIdx.x, t = threadIdx.x;
    int s = 0;
    if (t < CH / 4) {
        int base = b * CH + t * 4;
        s = cnt[base] + cnt[base + 1] + cnt[base + 2] + cnt[base + 3];
    }
    sh[t] = s;
    __syncthreads();
    if (t == 0) {
        int tot = 0;
        for (int i = 0; i < CH / 4; i++) tot += sh[i];
        bsum[b] = tot;
    }
}

__global__ void k_scan2(const int* __restrict__ bsum, int* __restrict__ bpre,
                        int* __restrict__ off) {
    if (threadIdx.x == 0) {
        int run = 0;
        for (int i = 0; i < NB_SCAN; i++) { bpre[i] = run; run += bsum[i]; }
        off[NN] = NE;
    }
}

__global__ void k_scan3(const int* __restrict__ cnt, const int* __restrict__ bpre,
                        int* __restrict__ off, int* __restrict__ cur,
                        float* __restrict__ rdeg) {
    __shared__ int sh[256];
    int b = blockIdx.x, t = threadIdx.x;
    int base = b * CH + t * 4;
    int c0 = 0, c1 = 0, c2 = 0, c3 = 0, s = 0;
    if (t < CH / 4) {
        c0 = cnt[base]; c1 = cnt[base + 1]; c2 = cnt[base + 2]; c3 = cnt[base + 3];
        s = c0 + c1 + c2 + c3;
    }
    sh[t] = s;
    __syncthreads();
    if (t == 0) {
        int run = bpre[b];
        for (int i = 0; i < CH / 4; i++) { int v = sh[i]; sh[i] = run; run += v; }
    }
    __syncthreads();
    if (t < CH / 4) {
        int run = sh[t];
        off[base] = run; cur[base] = run; run += c0;
        off[base + 1] = run; cur[base + 1] = run; run += c1;
        off[base + 2] = run; cur[base + 2] = run; run += c2;
        off[base + 3] = run; cur[base + 3] = run;
        rdeg[base]     = 1.0f / (float)(c0 + 1);
        rdeg[base + 1] = 1.0f / (float)(c1 + 1);
        rdeg[base + 2] = 1.0f / (float)(c2 + 1);
        rdeg[base + 3] = 1.0f / (float)(c3 + 1);
    }
}

__global__ void k_bucket(const int* __restrict__ src, const int* __restrict__ dst,
                         const int* __restrict__ efeat, int* __restrict__ cur,
                         int* __restrict__ esrc, int* __restrict__ eft) {
    int e = blockIdx.x * blockDim.x + threadIdx.x;
    if (e < NE) {
        int p = atomicAdd(&cur[dst[e]], 1);
        esrc[p] = src[e];
        eft[p] = efeat[e];
    }
}

// ---------------- degree-sorted padded edge lists + per-row feat histogram ----------------
// pent[b][j][16] = src | feat<<18 (layers 1+); pent0 = nfeat[src] | feat<<18 (layer 0)
// sentinel feat=5 (zero edge row, weight 0). ALL MAXD slots sentinel-filled.
// hist[n] = packed 6-bit counts of feats 0..4 (full degree), via LDS int atomics.
__global__ void k_pad(const int* __restrict__ off, const int* __restrict__ esrc,
                      const int* __restrict__ eft, const int* __restrict__ nfeat,
                      int* __restrict__ pent, int* __restrict__ pent0,
                      int* __restrict__ bperm, int* __restrict__ gmax,
                      int* __restrict__ hist) {
    __shared__ int offL[BM + 1];
    __shared__ int degS[BM];
    __shared__ int sortIdx[BM];
    __shared__ int histS[BM];
    int b = blockIdx.x, tid = threadIdx.x;
    if (tid <= BM) offL[tid] = off[b * BM + tid];
    if (tid < BM) histS[tid] = 0;
    __syncthreads();
    if (tid < BM) degS[tid] = offL[tid + 1] - offL[tid];
    __syncthreads();
    if (tid < BM) {
        int d = degS[tid], rank = 0;
        #pragma unroll
        for (int j = 0; j < BM; j++)
            rank += (degS[j] > d) || (degS[j] == d && j < tid);
        sortIdx[rank] = tid;
    }
    __syncthreads();
    if (tid < 8) gmax[b * 8 + tid] = degS[sortIdx[tid * 2]];  // sorted desc -> pair max
    if (tid < BM) bperm[b * BM + tid] = sortIdx[tid];
    __syncthreads();
    {
        int idx = tid;                     // BM*MAXD = 256, one per thread
        int p = idx & 15, j = idx >> 4;
        int row = sortIdx[p];
        int d = degS[row];
        int v, v0;
        if (j < d) {
            int e = offL[row] + j;
            int s = esrc[e], f = eft[e];
            v = s | (f << 18);
            v0 = nfeat[s] | (f << 18);
            atomicAdd(&histS[row], 1 << (6 * f));   // LDS, <=16-way
        } else { v = (5 << 18); v0 = (5 << 18); }
        pent[(size_t)b * MAXD * BM + j * BM + p] = v;
        pent0[(size_t)b * MAXD * BM + j * BM + p] = v0;
    }
    __syncthreads();
    if (tid < BM) {
        int h = histS[tid];
        if (degS[tid] > MAXD) {            // rare: count edges beyond MAXD
            for (int e = offL[tid] + MAXD; e < offL[tid + 1]; e++)
                h += 1 << (6 * eft[e]);
        }
        hist[b * BM + tid] = h;
    }
}

// ---------------- fused layer (BM=16; (256,6); hist-hoisted e-sum; x4 gather) ----------------
// Layers 1+: 4 slots/trip -> 8 independent uint2 gathers in flight per trip
// (vs 4 in r10), halving latency-exposed trips. Trip count rounds to x4 via the
// sentinel-filled slots (weight 0, row-0 gather = L2-hot numeric no-op).
__global__ __launch_bounds__(256, 6)
void k_fused(const void* __restrict__ basep, const int* __restrict__ nfeat, int first,
             const int* __restrict__ off, const int* __restrict__ esrc,
             const int* __restrict__ pentsel,
             const int* __restrict__ bperm, const int* __restrict__ gmax,
             const int* __restrict__ hist,
             const float* __restrict__ eemb, const float* __restrict__ rdeg,
             const float* __restrict__ scP, const float* __restrict__ shP,
             const unsigned short* __restrict__ Wht, const unsigned short* __restrict__ Wlt,
             const float* __restrict__ bias,
             unsigned short* __restrict__ C, float* __restrict__ part) {
    __shared__ unsigned short Xh[BM * XS];   // 4352 B (reused as C repack buffer)
    __shared__ unsigned short Xl[BM * XS];   // 4352 B
    __shared__ float eSr[6 * DD];            // eemb (5 rows) in gather, red in epilogue
    __shared__ int pentL[BM * MAXD];         // 1024 B
    __shared__ int offL[BM + 1];
    __shared__ int permL[BM];
    __shared__ int gmL[8];

    const float* baseF = (const float*)basep;                   // first: atom_emb fp32
    const unsigned short* baseB = (const unsigned short*)basep; // else: h bf16

    int tid = threadIdx.x;
    int n0 = blockIdx.x * BM;
    if (tid < 160) *(float4*)(eSr + tid * 4) = *(const float4*)(eemb + tid * 4);
    if (tid <= BM) offL[tid] = off[n0 + tid];
    if (tid < BM) permL[tid] = bperm[blockIdx.x * BM + tid];
    if (tid < 8) gmL[tid] = gmax[blockIdx.x * 8 + tid];
    pentL[tid] = pentsel[(size_t)blockIdx.x * MAXD * BM + tid];   // 256 ints

    int lane32 = tid & 31, grp = tid >> 5;     // 8 groups x 2 rows
    int c4 = lane32 << 2;
    float4 sc4, sh4;
    if (!first) {
        sc4 = *(const float4*)(scP + c4);
        sh4 = *(const float4*)(shP + c4);
    }
    __syncthreads();

    int rows[2];
    #pragma unroll
    for (int i = 0; i < 2; i++) rows[i] = permL[grp * 2 + i];

    // histogram words for this group's 2 rows (broadcast loads, issued early)
    int hw[2];
    #pragma unroll
    for (int i = 0; i < 2; i++) hw[i] = hist[n0 + rows[i]];

    // ---- self-init ----
    float4 acc[2];
    #pragma unroll
    for (int i = 0; i < 2; i++) {
        int n = n0 + rows[i];
        if (first) {
            acc[i] = *(const float4*)(baseF + (size_t)nfeat[n] * DD + c4);
        } else {
            uint2 g = *(const uint2*)(baseB + (size_t)n * DD + c4);
            acc[i] = actv4(bf4_to_f4(g), sc4, sh4);
        }
    }

    // ---- lockstep padded edge loop (no per-edge e-add) ----
    int gmx = gmL[grp];
    int jmax = gmx < MAXD ? gmx : MAXD;
    const int* pL = pentL + grp * 2;
    if (first) {
        int j = 0;
        for (; j + 2 <= jmax; j += 2) {
            int a0 = pL[j*16+0], a1 = pL[j*16+1];
            int b0 = pL[j*16+16], b1 = pL[j*16+17];
            float4 ha0 = *(const float4*)(baseF + (size_t)(a0 & 0x3FFFF) * DD + c4);
            float4 ha1 = *(const float4*)(baseF + (size_t)(a1 & 0x3FFFF) * DD + c4);
            float4 hb0 = *(const float4*)(baseF + (size_t)(b0 & 0x3FFFF) * DD + c4);
            float4 hb1 = *(const float4*)(baseF + (size_t)(b1 & 0x3FFFF) * DD + c4);
            float wa0 = ((a0 >> 18) == 5) ? 0.f : 1.f, wa1 = ((a1 >> 18) == 5) ? 0.f : 1.f;
            float wb0 = ((b0 >> 18) == 5) ? 0.f : 1.f, wb1 = ((b1 >> 18) == 5) ? 0.f : 1.f;
            acc[0].x += ha0.x * wa0 + hb0.x * wb0;
            acc[0].y += ha0.y * wa0 + hb0.y * wb0;
            acc[0].z += ha0.z * wa0 + hb0.z * wb0;
            acc[0].w += ha0.w * wa0 + hb0.w * wb0;
            acc[1].x += ha1.x * wa1 + hb1.x * wb1;
            acc[1].y += ha1.y * wa1 + hb1.y * wb1;
            acc[1].z += ha1.z * wa1 + hb1.z * wb1;
            acc[1].w += ha1.w * wa1 + hb1.w * wb1;
        }
        for (; j < jmax; j++) {
            int a0 = pL[j*16+0], a1 = pL[j*16+1];
            float4 h0 = *(const float4*)(baseF + (size_t)(a0 & 0x3FFFF) * DD + c4);
            float4 h1 = *(const float4*)(baseF + (size_t)(a1 & 0x3FFFF) * DD + c4);
            float w0 = ((a0 >> 18) == 5) ? 0.f : 1.f, w1 = ((a1 >> 18) == 5) ? 0.f : 1.f;
            acc[0].x += h0.x * w0; acc[0].y += h0.y * w0;
            acc[0].z += h0.z * w0; acc[0].w += h0.w * w0;
            acc[1].x += h1.x * w1; acc[1].y += h1.y * w1;
            acc[1].z += h1.z * w1; acc[1].w += h1.w * w1;
        }
    } else {
        // x4: trips rounded up via sentinel slots (weight 0 -> exact no-op)
        int jE = (jmax + 3) & ~3;          // 0,4,8,12,16
        for (int j = 0; j < jE; j += 4) {
            int p00 = pL[(j+0)*16+0], p01 = pL[(j+0)*16+1];
            int p10 = pL[(j+1)*16+0], p11 = pL[(j+1)*16+1];
            int p20 = pL[(j+2)*16+0], p21 = pL[(j+2)*16+1];
            int p30 = pL[(j+3)*16+0], p31 = pL[(j+3)*16+1];
            uint2 g00 = *(const uint2*)(baseB + (size_t)(p00 & 0x3FFFF) * DD + c4);
            uint2 g01 = *(const uint2*)(baseB + (size_t)(p01 & 0x3FFFF) * DD + c4);
            uint2 g10 = *(const uint2*)(baseB + (size_t)(p10 & 0x3FFFF) * DD + c4);
            uint2 g11 = *(const uint2*)(baseB + (size_t)(p11 & 0x3FFFF) * DD + c4);
            uint2 g20 = *(const uint2*)(baseB + (size_t)(p20 & 0x3FFFF) * DD + c4);
            uint2 g21 = *(const uint2*)(baseB + (size_t)(p21 & 0x3FFFF) * DD + c4);
            uint2 g30 = *(const uint2*)(baseB + (size_t)(p30 & 0x3FFFF) * DD + c4);
            uint2 g31 = *(const uint2*)(baseB + (size_t)(p31 & 0x3FFFF) * DD + c4);
            float4 h00 = actv4(bf4_to_f4(g00), sc4, sh4);
            float4 h01 = actv4(bf4_to_f4(g01), sc4, sh4);
            float4 h10 = actv4(bf4_to_f4(g10), sc4, sh4);
            float4 h11 = actv4(bf4_to_f4(g11), sc4, sh4);
            float4 h20 = actv4(bf4_to_f4(g20), sc4, sh4);
            float4 h21 = actv4(bf4_to_f4(g21), sc4, sh4);
            float4 h30 = actv4(bf4_to_f4(g30), sc4, sh4);
            float4 h31 = actv4(bf4_to_f4(g31), sc4, sh4);
            float w00 = ((p00 >> 18) == 5) ? 0.f : 1.f, w01 = ((p01 >> 18) == 5) ? 0.f : 1.f;
            float w10 = ((p10 >> 18) == 5) ? 0.f : 1.f, w11 = ((p11 >> 18) == 5) ? 0.f : 1.f;
            float w20 = ((p20 >> 18) == 5) ? 0.f : 1.f, w21 = ((p21 >> 18) == 5) ? 0.f : 1.f;
            float w30 = ((p30 >> 18) == 5) ? 0.f : 1.f, w31 = ((p31 >> 18) == 5) ? 0.f : 1.f;
            acc[0].x += h00.x * w00 + h10.x * w10 + h20.x * w20 + h30.x * w30;
            acc[0].y += h00.y * w00 + h10.y * w10 + h20.y * w20 + h30.y * w30;
            acc[0].z += h00.z * w00 + h10.z * w10 + h20.z * w20 + h30.z * w30;
            acc[0].w += h00.w * w00 + h10.w * w10 + h20.w * w20 + h30.w * w30;
            acc[1].x += h01.x * w01 + h11.x * w11 + h21.x * w21 + h31.x * w31;
            acc[1].y += h01.y * w01 + h11.y * w11 + h21.y * w21 + h31.y * w31;
            acc[1].z += h01.z * w01 + h11.z * w11 + h21.z * w21 + h31.z * w31;
            acc[1].w += h01.w * w01 + h11.w * w11 + h21.w * w21 + h31.w * w31;
        }
    }

    // ---- rare fallback: rows with deg > MAXD (h only; e covered by hist) ----
    if (gmx > MAXD) {
        #pragma unroll
        for (int i = 0; i < 2; i++) {
            int row = rows[i];
            for (int e = offL[row] + MAXD; e < offL[row + 1]; e++) {
                int s = esrc[e];
                float4 hv;
                if (first) {
                    hv = *(const float4*)(baseF + (size_t)nfeat[s] * DD + c4);
                } else {
                    uint2 g = *(const uint2*)(baseB + (size_t)s * DD + c4);
                    hv = actv4(bf4_to_f4(g), sc4, sh4);
                }
                acc[i].x += hv.x; acc[i].y += hv.y;
                acc[i].z += hv.z; acc[i].w += hv.w;
            }
        }
    }

    // ---- edge-embedding contribution: acc += sum_f count_f * e[f] ----
    #pragma unroll
    for (int i = 0; i < 2; i++) {
        float4 es = {0.f, 0.f, 0.f, 0.f};
        #pragma unroll
        for (int f = 0; f < 5; f++) {
            float cf = (float)((hw[i] >> (6 * f)) & 63);
            float4 ev = *(const float4*)(eSr + f * DD + c4);
            es.x += cf * ev.x; es.y += cf * ev.y;
            es.z += cf * ev.z; es.w += cf * ev.w;
        }
        acc[i].x += es.x; acc[i].y += es.y;
        acc[i].z += es.z; acc[i].w += es.w;
    }

    // ---- rdeg + bf16 hi/lo split -> LDS (write at original row index) ----
    #pragma unroll
    for (int i = 0; i < 2; i++) {
        int r = rows[i];
        float rd = rdeg[n0 + r];
        float ax = acc[i].x * rd, ay = acc[i].y * rd, az = acc[i].z * rd, aw = acc[i].w * rd;
        unsigned short h0 = f2bf(ax), h1 = f2bf(ay), h2 = f2bf(az), h3 = f2bf(aw);
        unsigned short l0 = f2bf(ax - bf2f(h0));
        unsigned short l1 = f2bf(ay - bf2f(h1));
        unsigned short l2 = f2bf(az - bf2f(h2));
        unsigned short l3 = f2bf(aw - bf2f(h3));
        uint2 hv2, lv2;
        hv2.x = (unsigned)h0 | ((unsigned)h1 << 16);
        hv2.y = (unsigned)h2 | ((unsigned)h3 << 16);
        lv2.x = (unsigned)l0 | ((unsigned)l1 << 16);
        lv2.y = (unsigned)l2 | ((unsigned)l3 << 16);
        *(uint2*)(Xh + r * XS + c4) = hv2;
        *(uint2*)(Xl + r * XS + c4) = lv2;
    }
    __syncthreads();

    // ---- MFMA: 4 waves; one 16-row tile, wave w -> cols [w*32, w*32+32) ----
    int lane = tid & 63, w = tid >> 6;
    int m16 = lane & 15, quad = lane >> 4;
    int colBase = w << 5;

    floatx4 acc4[2];
    #pragma unroll
    for (int t = 0; t < 2; t++) acc4[t] = (floatx4){0.f, 0.f, 0.f, 0.f};

    #pragma unroll
    for (int kp = 0; kp < 4; kp++) {
        bf16x8 ah = *(const bf16x8*)(Xh + m16 * XS + kp * 32 + quad * 8);
        bf16x8 al = *(const bf16x8*)(Xl + m16 * XS + kp * 32 + quad * 8);
        #pragma unroll
        for (int t = 0; t < 2; t++) {
            int ncol = colBase + t * 16 + m16;
            bf16x8 bh = *(const bf16x8*)(Wht + (size_t)ncol * DD + kp * 32 + quad * 8);
            bf16x8 bl = *(const bf16x8*)(Wlt + (size_t)ncol * DD + kp * 32 + quad * 8);
            acc4[t] = __builtin_amdgcn_mfma_f32_16x16x32_bf16(ah, bh, acc4[t], 0, 0, 0);
            acc4[t] = __builtin_amdgcn_mfma_f32_16x16x32_bf16(ah, bl, acc4[t], 0, 0, 0);
            acc4[t] = __builtin_amdgcn_mfma_f32_16x16x32_bf16(al, bh, acc4[t], 0, 0, 0);
        }
    }
    __syncthreads();   // MFMA reads done -> Xh reusable as C buffer, eSr as red

    // ---- epilogue: bias, BN partials (fp32), pack bf16 C into LDS ----
    float* redS = eSr;
    float* redQ = eSr + DD;
    unsigned short* Cs = Xh;
    #pragma unroll
    for (int t = 0; t < 2; t++) {
        int col = colBase + t * 16 + m16;
        float bv = bias[col];
        float s = 0.f, q = 0.f;
        #pragma unroll
        for (int rr = 0; rr < 4; rr++) {
            float vv = acc4[t][rr] + bv;
            s += vv; q += vv * vv;
            Cs[(quad * 4 + rr) * XS + col] = f2bf(vv);
        }
        s += __shfl_xor(s, 16); q += __shfl_xor(q, 16);
        s += __shfl_xor(s, 32); q += __shfl_xor(q, 32);
        if (lane < 16) { redS[col] = s; redQ[col] = q; }
    }
    __syncthreads();

    // ---- coalesced bf16 C store (16 rows x 16 uint4 = 256 = one per thread) ----
    {
        int row = tid >> 4, q16 = tid & 15;
        uint4 v = *(const uint4*)(Cs + row * XS + q16 * 8);
        *(uint4*)(C + (size_t)(n0 + row) * DD + q16 * 8) = v;
    }
    if (tid < DD) {
        part[(size_t)blockIdx.x * 256 + tid] = redS[tid];
        part[(size_t)blockIdx.x * 256 + DD + tid] = redQ[tid];
    }
}

// ---------------- BN stat reduce + last-block finalize -> scale/shift ----------------
__global__ void k_stats(const float* __restrict__ part, float* __restrict__ acc,
                        int* __restrict__ cnt,
                        const float* __restrict__ gamma, const float* __restrict__ beta,
                        float* __restrict__ scale, float* __restrict__ shift) {
    int t = threadIdx.x;
    float s = 0.f;
    int base = blockIdx.x * (NBLK / SB);
    for (int i = 0; i < NBLK / SB; i++)
        s += part[(size_t)(base + i) * 256 + t];
    atomicAdd(&acc[t], s);
    __threadfence();
    __shared__ int lastS;
    __syncthreads();
    if (t == 0) lastS = (atomicAdd(cnt, 1) == SB - 1);
    __syncthreads();
    if (lastS && t < DD) {
        float Sv = atomicAdd(&acc[t], 0.0f);
        float Qv = atomicAdd(&acc[DD + t], 0.0f);
        float m = Sv / (float)NN;
        float v = Qv / (float)NN - m * m;
        float rs = rsqrtf(v + EPS);
        float sc = rs * gamma[t];
        scale[t] = sc;
        shift[t] = beta[t] - m * sc;
    }
}

// ---------------- last layer: act fused with graph-sum pooling (bf16 h) ----------------
__global__ void k_bnpool(const unsigned short* __restrict__ A, const int* __restrict__ n2g,
                         const float* __restrict__ scale, const float* __restrict__ shift,
                         float* __restrict__ gsum) {
    int tid = threadIdx.x;
    int stripe = tid >> 5, lane = tid & 31;
    int c4 = lane << 2;
    int n0 = blockIdx.x * PCH;
    float4 sc4 = *(const float4*)(scale + c4);
    float4 sh4 = *(const float4*)(shift + c4);
    float4 acc = {0.f, 0.f, 0.f, 0.f};
    int cur = n2g[n0 + stripe];
    for (int i = 0; i < PCH / 8; i++) {
        int n = n0 + i * 8 + stripe;
        int gg = n2g[n];
        if (gg != cur) {
            atomicAdd(&gsum[(size_t)cur * DD + c4 + 0], acc.x);
            atomicAdd(&gsum[(size_t)cur * DD + c4 + 1], acc.y);
            atomicAdd(&gsum[(size_t)cur * DD + c4 + 2], acc.z);
            atomicAdd(&gsum[(size_t)cur * DD + c4 + 3], acc.w);
            acc = (float4){0.f, 0.f, 0.f, 0.f};
            cur = gg;
        }
        uint2 v = *(const uint2*)(A + (size_t)n * DD + c4);
        float4 x = bf4_to_f4(v);
        acc.x += fmaxf(0.f, x.x * sc4.x + sh4.x);
        acc.y += fmaxf(0.f, x.y * sc4.y + sh4.y);
        acc.z += fmaxf(0.f, x.z * sc4.z + sh4.z);
        acc.w += fmaxf(0.f, x.w * sc4.w + sh4.w);
    }
    atomicAdd(&gsum[(size_t)cur * DD + c4 + 0], acc.x);
    atomicAdd(&gsum[(size_t)cur * DD + c4 + 1], acc.y);
    atomicAdd(&gsum[(size_t)cur * DD + c4 + 2], acc.z);
    atomicAdd(&gsum[(size_t)cur * DD + c4 + 3], acc.w);
}

// ---------------- final MLP ----------------
__global__ void k_mlp(const float* __restrict__ gsum, const float* __restrict__ gcnt,
                      const float* __restrict__ W1, const float* __restrict__ b1,
                      const float* __restrict__ W2, const float* __restrict__ b2,
                      float* __restrict__ out) {
    __shared__ float gs[DD], hs[DD];
    int gid = blockIdx.x, j = threadIdx.x;
    float inv = 1.0f / fmaxf(gcnt[gid], 1.0f);
    gs[j] = gsum[(size_t)gid * DD + j] * inv;
    __syncthreads();
    float a = b1[j];
    for (int k = 0; k < DD; k++) a += gs[k] * W1[k * DD + j];
    hs[j] = fmaxf(a, 0.f);
    __syncthreads();
    float o = b2[j];
    for (int k = 0; k < DD; k++) o += hs[k] * W2[k * DD + j];
    out[(size_t)gid * DD + j] = o;
}

extern "C" void kernel_launch(void* const* d_in, const int* in_sizes, int n_in,
                              void* d_out, int out_size, void* d_ws, size_t ws_size,
                              hipStream_t stream) {
    const int*   nfeat = (const int*)d_in[0];
    const int*   efeat = (const int*)d_in[1];
    const int*   src   = (const int*)d_in[2];
    const int*   dst   = (const int*)d_in[3];
    const int*   n2g   = (const int*)d_in[4];
    const float* aemb  = (const float*)d_in[5];
    const float* eemb  = (const float*)d_in[6];   // [L][5][128]
    const float* Wl    = (const float*)d_in[7];   // [L][128][128]
    const float* bl    = (const float*)d_in[8];   // [L][128]
    const float* gam   = (const float*)d_in[9];
    const float* bet   = (const float*)d_in[10];
    const float* W1    = (const float*)d_in[11];
    const float* b1    = (const float*)d_in[12];
    const float* W2    = (const float*)d_in[13];
    const float* b2    = (const float*)d_in[14];
    float* out = (float*)d_out;

    unsigned short* H0 = (unsigned short*)d_ws;          // NN*DD bf16
    unsigned short* H1 = H0 + (size_t)NN * DD;           // NN*DD bf16
    float* rdeg   = (float*)(H1 + (size_t)NN * DD);      // NN
    float* gsum   = rdeg + NN;                           // NG*DD
    float* gcnt   = gsum + (size_t)NG * DD;              // NG
    float* scaleA = gcnt + NG;                           // NL*DD
    float* shiftA = scaleA + NL * DD;                    // NL*DD
    float* accS   = shiftA + NL * DD;                    // NL*256
    int*   scnt   = (int*)(accS + NL * 256);             // 16
    float* part   = (float*)(scnt + 16);                 // NBLK*256 floats (12.8 MB)
    unsigned short* Wht = (unsigned short*)(part + (size_t)NBLK * 256);  // NL*DD*DD
    unsigned short* Wlt = Wht + (size_t)NL * DD * DD;
    int* off   = (int*)(Wlt + (size_t)NL * DD * DD);     // NN+1
    int* cur   = off + NN + 1;                           // NN (reused as hist after k_bucket)
    int* esrc  = cur + NN;                               // NE
    int* eft   = esrc + NE;                              // NE
    int* cnt   = eft + NE;                               // NN
    int* bsum  = cnt + NN;                               // NB_SCAN
    int* bpre  = bsum + NB_SCAN;                         // NB_SCAN
    int* bperm = bpre + NB_SCAN;                         // NBLK*16
    int* gmax  = bperm + (size_t)NBLK * BM;              // NBLK*8
    int* pent  = gmax + (size_t)NBLK * 8;                // NBLK*MAXD*BM (12.8 MB)
    int* pent0 = pent + (size_t)NBLK * MAXD * BM;        // NBLK*MAXD*BM (12.8 MB)
    int* hist  = cur;                                    // NN ints: cur is dead after k_bucket

    hipMemsetAsync(gsum, 0, (size_t)(NG * DD + NG) * sizeof(float), stream);
    hipMemsetAsync(accS, 0, (size_t)(NL * 256) * sizeof(float) + 16 * sizeof(int), stream);
    hipMemsetAsync(cnt, 0, (size_t)NN * sizeof(int), stream);

    k_setup1<<<(NE + 255) / 256, 256, 0, stream>>>(dst, cnt, n2g, gcnt, Wl, Wht, Wlt);
    k_scan1<<<NB_SCAN, 256, 0, stream>>>(cnt, bsum);
    k_scan2<<<1, 64, 0, stream>>>(bsum, bpre, off);
    k_scan3<<<NB_SCAN, 256, 0, stream>>>(cnt, bpre, off, cur, rdeg);
    k_bucket<<<(NE + 255) / 256, 256, 0, stream>>>(src, dst, efeat, cur, esrc, eft);
    k_pad<<<NBLK, 256, 0, stream>>>(off, esrc, eft, nfeat, pent, pent0, bperm, gmax, hist);

    unsigned short* hcur = H0;
    for (int l = 0; l < NL; l++) {
        const void* base = (l == 0) ? (const void*)aemb : (const void*)hcur;
        unsigned short* hnext = (l == 0) ? H0 : ((hcur == H0) ? H1 : H0);
        const int* psel = (l == 0) ? pent0 : pent;
        const float* scP = scaleA + (size_t)((l == 0) ? 0 : (l - 1)) * DD;
        const float* shP = shiftA + (size_t)((l == 0) ? 0 : (l - 1)) * DD;
        k_fused<<<NBLK, 256, 0, stream>>>(base, nfeat, (l == 0) ? 1 : 0,
                                          off, esrc, psel, bperm, gmax, hist,
                                          eemb + (size_t)l * BOND_V * DD, rdeg,
                                          scP, shP,
                                          Wht + (size_t)l * DD * DD,
                                          Wlt + (size_t)l * DD * DD,
                                          bl + (size_t)l * DD, hnext, part);
        k_stats<<<SB, 256, 0, stream>>>(part, accS + l * 256, scnt + l,
                                        gam + (size_t)l * DD, bet + (size_t)l * DD,
                                        scaleA + (size_t)l * DD, shiftA + (size_t)l * DD);
        hcur = hnext;
    }
    k_bnpool<<<NN / PCH, 256, 0, stream>>>(hcur, n2g,
                                           scaleA + (size_t)(NL - 1) * DD,
                                           shiftA + (size_t)(NL - 1) * DD, gsum);
    k_mlp<<<NG, DD, 0, stream>>>(gsum, gcnt, W1, b1, W2, b2, out);
}

// Round 12
// 1001.951 us; speedup vs baseline: 1.0145x; 1.0145x over previous
//
#include <hip/hip_runtime.h>
#include <hip/hip_bf16.h>
#include <cstddef>

#define NN 200000   // nodes
#define NE 400000   // edges
#define DD 128      // embed dim
#define NL 5        // layers
#define NG 1000     // graphs
#define BOND_V 5
#define BM 16             // rows per fused block
#define NBLK (NN / BM)    // 12500
#define MAXD 16           // padded edge slots per row (deg>16 -> serial fallback)
#define PCH 200           // pool rows per block (1000 blocks)
#define NB_SCAN 200
#define CH 1000
#define SB 125            // k_stats blocks (500 regressed r9: atomic contention)
#define EPS 1e-5f
#define XS 136            // Xh/Xl row stride (shorts), 272B = 17*16 -> b128-aligned

typedef __bf16 bf16x8 __attribute__((ext_vector_type(8)));
typedef float floatx4 __attribute__((ext_vector_type(4)));

__device__ __forceinline__ unsigned short f2bf(float f) {
    unsigned int u = __float_as_uint(f);
    u = (u + 0x7fffu + ((u >> 16) & 1u)) >> 16;
    return (unsigned short)u;
}
__device__ __forceinline__ float bf2f(unsigned short s) {
    return __uint_as_float(((unsigned int)s) << 16);
}
__device__ __forceinline__ float4 bf4_to_f4(uint2 v) {
    float4 o;
    o.x = __uint_as_float(v.x << 16);
    o.y = __uint_as_float(v.x & 0xffff0000u);
    o.z = __uint_as_float(v.y << 16);
    o.w = __uint_as_float(v.y & 0xffff0000u);
    return o;
}
__device__ __forceinline__ float4 actv4(float4 h, float4 sc, float4 sh) {
    float4 o;
    o.x = fmaxf(0.f, h.x * sc.x + sh.x);
    o.y = fmaxf(0.f, h.y * sc.y + sh.y);
    o.z = fmaxf(0.f, h.z * sc.z + sh.z);
    o.w = fmaxf(0.f, h.w * sc.w + sh.w);
    return o;
}

// ---------------- merged setup: degree cnt, graph cnt, W split ----------------
__global__ void k_setup1(const int* __restrict__ dst, int* __restrict__ cnt,
                         const int* __restrict__ n2g, float* __restrict__ gcnt,
                         const float* __restrict__ W, unsigned short* __restrict__ Wht,
                         unsigned short* __restrict__ Wlt) {
    int e = blockIdx.x * blockDim.x + threadIdx.x;
    if (e < NE) atomicAdd(&cnt[dst[e]], 1);
    if (e < NN) atomicAdd(&gcnt[n2g[e]], 1.0f);
    if (e < NL * DD * DD) {
        int l = e / (DD * DD), rem = e % (DD * DD);
        int k = rem / DD, n = rem % DD;
        float v = W[e];
        unsigned short hb = f2bf(v);
        unsigned short lb = f2bf(v - bf2f(hb));
        size_t o = (size_t)l * DD * DD + (size_t)n * DD + k;
        Wht[o] = hb; Wlt[o] = lb;
    }
}

// ---------------- CSR build ----------------
__global__ void k_scan1(const int* __restrict__ cnt, int* __restrict__ bsum) {
    __shared__ int sh[256];
    int b = blockIdx.x, t = threadIdx.x;
    int s = 0;
    if (t < CH / 4) {
        int base = b * CH + t * 4;
        s = cnt[base] + cnt[base + 1] + cnt[base + 2] + cnt[base + 3];
    }
    sh[t] = s;
    __syncthreads();
    if (t == 0) {
        int tot = 0;
        for (int i = 0; i < CH / 4; i++) tot += sh[i];
        bsum[b] = tot;
    }
}

__global__ void k_scan2(const int* __restrict__ bsum, int* __restrict__ bpre,
                        int* __restrict__ off) {
    if (threadIdx.x == 0) {
        int run = 0;
        for (int i = 0; i < NB_SCAN; i++) { bpre[i] = run; run += bsum[i]; }
        off[NN] = NE;
    }
}

__global__ void k_scan3(const int* __restrict__ cnt, const int* __restrict__ bpre,
                        int* __restrict__ off, int* __restrict__ cur,
                        float* __restrict__ rdeg) {
    __shared__ int sh[256];
    int b = blockIdx.x, t = threadIdx.x;
    int base = b * CH + t * 4;
    int c0 = 0, c1 = 0, c2 = 0, c3 = 0, s = 0;
    if (t < CH / 4) {
        c0 = cnt[base]; c1 = cnt[base + 1]; c2 = cnt[base + 2]; c3 = cnt[base + 3];
        s = c0 + c1 + c2 + c3;
    }
    sh[t] = s;
    __syncthreads();
    if (t == 0) {
        int run = bpre[b];
        for (int i = 0; i < CH / 4; i++) { int v = sh[i]; sh[i] = run; run += v; }
    }
    __syncthreads();
    if (t < CH / 4) {
        int run = sh[t];
        off[base] = run; cur[base] = run; run += c0;
        off[base + 1] = run; cur[base + 1] = run; run += c1;
        off[base + 2] = run; cur[base + 2] = run; run += c2;
        off[base + 3] = run; cur[base + 3] = run;
        rdeg[base]     = 1.0f / (float)(c0 + 1);
        rdeg[base + 1] = 1.0f / (float)(c1 + 1);
        rdeg[base + 2] = 1.0f / (float)(c2 + 1);
        rdeg[base + 3] = 1.0f / (float)(c3 + 1);
    }
}

__global__ void k_bucket(const int* __restrict__ src, const int* __restrict__ dst,
                         const int* __restrict__ efeat, int* __restrict__ cur,
                         int* __restrict__ esrc, int* __restrict__ eft) {
    int e = blockIdx.x * blockDim.x + threadIdx.x;
    if (e < NE) {
        int p = atomicAdd(&cur[dst[e]], 1);
        esrc[p] = src[e];
        eft[p] = efeat[e];
    }
}

// ---------------- degree-sorted padded edge lists + per-row feat histogram ----------------
// pent[b][j][16] = src | feat<<18 (layers 1+); pent0 = nfeat[src] | feat<<18 (layer 0)
// sentinel feat=5 (zero edge row, weight 0). ALL MAXD slots sentinel-filled.
// hist[n] = packed 6-bit counts of feats 0..4 (full degree), via LDS int atomics.
__global__ void k_pad(const int* __restrict__ off, const int* __restrict__ esrc,
                      const int* __restrict__ eft, const int* __restrict__ nfeat,
                      int* __restrict__ pent, int* __restrict__ pent0,
                      int* __restrict__ bperm, int* __restrict__ gmax,
                      int* __restrict__ hist) {
    __shared__ int offL[BM + 1];
    __shared__ int degS[BM];
    __shared__ int sortIdx[BM];
    __shared__ int histS[BM];
    int b = blockIdx.x, tid = threadIdx.x;
    if (tid <= BM) offL[tid] = off[b * BM + tid];
    if (tid < BM) histS[tid] = 0;
    __syncthreads();
    if (tid < BM) degS[tid] = offL[tid + 1] - offL[tid];
    __syncthreads();
    if (tid < BM) {
        int d = degS[tid], rank = 0;
        #pragma unroll
        for (int j = 0; j < BM; j++)
            rank += (degS[j] > d) || (degS[j] == d && j < tid);
        sortIdx[rank] = tid;
    }
    __syncthreads();
    if (tid < 8) gmax[b * 8 + tid] = degS[sortIdx[tid * 2]];  // sorted desc -> pair max
    if (tid < BM) bperm[b * BM + tid] = sortIdx[tid];
    __syncthreads();
    {
        int idx = tid;                     // BM*MAXD = 256, one per thread
        int p = idx & 15, j = idx >> 4;
        int row = sortIdx[p];
        int d = degS[row];
        int v, v0;
        if (j < d) {
            int e = offL[row] + j;
            int s = esrc[e], f = eft[e];
            v = s | (f << 18);
            v0 = nfeat[s] | (f << 18);
            atomicAdd(&histS[row], 1 << (6 * f));   // LDS, <=16-way
        } else { v = (5 << 18); v0 = (5 << 18); }
        pent[(size_t)b * MAXD * BM + j * BM + p] = v;
        pent0[(size_t)b * MAXD * BM + j * BM + p] = v0;
    }
    __syncthreads();
    if (tid < BM) {
        int h = histS[tid];
        if (degS[tid] > MAXD) {            // rare: count edges beyond MAXD
            for (int e = offL[tid] + MAXD; e < offL[tid + 1]; e++)
                h += 1 << (6 * eft[e]);
        }
        hist[b * BM + tid] = h;
    }
}

// ---------------- fused layer (BM=16; (256,7); hist-hoisted e-sum) ----------------
// Occupancy ladder: (256,4)=50% r0/r6; (256,6)=62% r8 (no spill, VGPR 40);
// (256,8) cap=64 spilled (r7: scheduler peak liveness > cap). (256,7) cap=73
// leaves 33 regs slack over the measured 40 -> 7 blocks/CU target.
__global__ __launch_bounds__(256, 7)
void k_fused(const void* __restrict__ basep, const int* __restrict__ nfeat, int first,
             const int* __restrict__ off, const int* __restrict__ esrc,
             const int* __restrict__ pentsel,
             const int* __restrict__ bperm, const int* __restrict__ gmax,
             const int* __restrict__ hist,
             const float* __restrict__ eemb, const float* __restrict__ rdeg,
             const float* __restrict__ scP, const float* __restrict__ shP,
             const unsigned short* __restrict__ Wht, const unsigned short* __restrict__ Wlt,
             const float* __restrict__ bias,
             unsigned short* __restrict__ C, float* __restrict__ part) {
    __shared__ unsigned short Xh[BM * XS];   // 4352 B (reused as C repack buffer)
    __shared__ unsigned short Xl[BM * XS];   // 4352 B
    __shared__ float eSr[6 * DD];            // eemb (5 rows) in gather, red in epilogue
    __shared__ int pentL[BM * MAXD];         // 1024 B
    __shared__ int offL[BM + 1];
    __shared__ int permL[BM];
    __shared__ int gmL[8];

    const float* baseF = (const float*)basep;                   // first: atom_emb fp32
    const unsigned short* baseB = (const unsigned short*)basep; // else: h bf16

    int tid = threadIdx.x;
    int n0 = blockIdx.x * BM;
    if (tid < 160) *(float4*)(eSr + tid * 4) = *(const float4*)(eemb + tid * 4);
    if (tid <= BM) offL[tid] = off[n0 + tid];
    if (tid < BM) permL[tid] = bperm[blockIdx.x * BM + tid];
    if (tid < 8) gmL[tid] = gmax[blockIdx.x * 8 + tid];
    pentL[tid] = pentsel[(size_t)blockIdx.x * MAXD * BM + tid];   // 256 ints

    int lane32 = tid & 31, grp = tid >> 5;     // 8 groups x 2 rows
    int c4 = lane32 << 2;
    float4 sc4, sh4;
    if (!first) {
        sc4 = *(const float4*)(scP + c4);
        sh4 = *(const float4*)(shP + c4);
    }
    __syncthreads();

    int rows[2];
    #pragma unroll
    for (int i = 0; i < 2; i++) rows[i] = permL[grp * 2 + i];

    // histogram words for this group's 2 rows (broadcast loads, issued early)
    int hw[2];
    #pragma unroll
    for (int i = 0; i < 2; i++) hw[i] = hist[n0 + rows[i]];

    // ---- self-init ----
    float4 acc[2];
    #pragma unroll
    for (int i = 0; i < 2; i++) {
        int n = n0 + rows[i];
        if (first) {
            acc[i] = *(const float4*)(baseF + (size_t)nfeat[n] * DD + c4);
        } else {
            uint2 g = *(const uint2*)(baseB + (size_t)n * DD + c4);
            acc[i] = actv4(bf4_to_f4(g), sc4, sh4);
        }
    }

    // ---- lockstep padded edge loop, unrolled x2 (no per-edge e-add) ----
    int gmx = gmL[grp];
    int jmax = gmx < MAXD ? gmx : MAXD;
    const int* pL = pentL + grp * 2;
    int j = 0;
    if (first) {
        for (; j + 2 <= jmax; j += 2) {
            int a0 = pL[j*16+0], a1 = pL[j*16+1];
            int b0 = pL[j*16+16], b1 = pL[j*16+17];
            float4 ha0 = *(const float4*)(baseF + (size_t)(a0 & 0x3FFFF) * DD + c4);
            float4 ha1 = *(const float4*)(baseF + (size_t)(a1 & 0x3FFFF) * DD + c4);
            float4 hb0 = *(const float4*)(baseF + (size_t)(b0 & 0x3FFFF) * DD + c4);
            float4 hb1 = *(const float4*)(baseF + (size_t)(b1 & 0x3FFFF) * DD + c4);
            float wa0 = ((a0 >> 18) == 5) ? 0.f : 1.f, wa1 = ((a1 >> 18) == 5) ? 0.f : 1.f;
            float wb0 = ((b0 >> 18) == 5) ? 0.f : 1.f, wb1 = ((b1 >> 18) == 5) ? 0.f : 1.f;
            acc[0].x += ha0.x * wa0 + hb0.x * wb0;
            acc[0].y += ha0.y * wa0 + hb0.y * wb0;
            acc[0].z += ha0.z * wa0 + hb0.z * wb0;
            acc[0].w += ha0.w * wa0 + hb0.w * wb0;
            acc[1].x += ha1.x * wa1 + hb1.x * wb1;
            acc[1].y += ha1.y * wa1 + hb1.y * wb1;
            acc[1].z += ha1.z * wa1 + hb1.z * wb1;
            acc[1].w += ha1.w * wa1 + hb1.w * wb1;
        }
        for (; j < jmax; j++) {
            int a0 = pL[j*16+0], a1 = pL[j*16+1];
            float4 h0 = *(const float4*)(baseF + (size_t)(a0 & 0x3FFFF) * DD + c4);
            float4 h1 = *(const float4*)(baseF + (size_t)(a1 & 0x3FFFF) * DD + c4);
            float w0 = ((a0 >> 18) == 5) ? 0.f : 1.f, w1 = ((a1 >> 18) == 5) ? 0.f : 1.f;
            acc[0].x += h0.x * w0; acc[0].y += h0.y * w0;
            acc[0].z += h0.z * w0; acc[0].w += h0.w * w0;
            acc[1].x += h1.x * w1; acc[1].y += h1.y * w1;
            acc[1].z += h1.z * w1; acc[1].w += h1.w * w1;
        }
    } else {
        for (; j + 2 <= jmax; j += 2) {
            int a0 = pL[j*16+0], a1 = pL[j*16+1];
            int b0 = pL[j*16+16], b1 = pL[j*16+17];
            uint2 ga0 = *(const uint2*)(baseB + (size_t)(a0 & 0x3FFFF) * DD + c4);
            uint2 ga1 = *(const uint2*)(baseB + (size_t)(a1 & 0x3FFFF) * DD + c4);
            uint2 gb0 = *(const uint2*)(baseB + (size_t)(b0 & 0x3FFFF) * DD + c4);
            uint2 gb1 = *(const uint2*)(baseB + (size_t)(b1 & 0x3FFFF) * DD + c4);
            float4 ha0 = actv4(bf4_to_f4(ga0), sc4, sh4);
            float4 ha1 = actv4(bf4_to_f4(ga1), sc4, sh4);
            float4 hb0 = actv4(bf4_to_f4(gb0), sc4, sh4);
            float4 hb1 = actv4(bf4_to_f4(gb1), sc4, sh4);
            float wa0 = ((a0 >> 18) == 5) ? 0.f : 1.f, wa1 = ((a1 >> 18) == 5) ? 0.f : 1.f;
            float wb0 = ((b0 >> 18) == 5) ? 0.f : 1.f, wb1 = ((b1 >> 18) == 5) ? 0.f : 1.f;
            acc[0].x += ha0.x * wa0 + hb0.x * wb0;
            acc[0].y += ha0.y * wa0 + hb0.y * wb0;
            acc[0].z += ha0.z * wa0 + hb0.z * wb0;
            acc[0].w += ha0.w * wa0 + hb0.w * wb0;
            acc[1].x += ha1.x * wa1 + hb1.x * wb1;
            acc[1].y += ha1.y * wa1 + hb1.y * wb1;
            acc[1].z += ha1.z * wa1 + hb1.z * wb1;
            acc[1].w += ha1.w * wa1 + hb1.w * wb1;
        }
        for (; j < jmax; j++) {
            int a0 = pL[j*16+0], a1 = pL[j*16+1];
            uint2 g0 = *(const uint2*)(baseB + (size_t)(a0 & 0x3FFFF) * DD + c4);
            uint2 g1 = *(const uint2*)(baseB + (size_t)(a1 & 0x3FFFF) * DD + c4);
            float4 h0 = actv4(bf4_to_f4(g0), sc4, sh4);
            float4 h1 = actv4(bf4_to_f4(g1), sc4, sh4);
            float w0 = ((a0 >> 18) == 5) ? 0.f : 1.f, w1 = ((a1 >> 18) == 5) ? 0.f : 1.f;
            acc[0].x += h0.x * w0; acc[0].y += h0.y * w0;
            acc[0].z += h0.z * w0; acc[0].w += h0.w * w0;
            acc[1].x += h1.x * w1; acc[1].y += h1.y * w1;
            acc[1].z += h1.z * w1; acc[1].w += h1.w * w1;
        }
    }

    // ---- rare fallback: rows with deg > MAXD (h only; e covered by hist) ----
    if (gmx > MAXD) {
        #pragma unroll
        for (int i = 0; i < 2; i++) {
            int row = rows[i];
            for (int e = offL[row] + MAXD; e < offL[row + 1]; e++) {
                int s = esrc[e];
                float4 hv;
                if (first) {
                    hv = *(const float4*)(baseF + (size_t)nfeat[s] * DD + c4);
                } else {
                    uint2 g = *(const uint2*)(baseB + (size_t)s * DD + c4);
                    hv = actv4(bf4_to_f4(g), sc4, sh4);
                }
                acc[i].x += hv.x; acc[i].y += hv.y;
                acc[i].z += hv.z; acc[i].w += hv.w;
            }
        }
    }

    // ---- edge-embedding contribution: acc += sum_f count_f * e[f] ----
    #pragma unroll
    for (int i = 0; i < 2; i++) {
        float4 es = {0.f, 0.f, 0.f, 0.f};
        #pragma unroll
        for (int f = 0; f < 5; f++) {
            float cf = (float)((hw[i] >> (6 * f)) & 63);
            float4 ev = *(const float4*)(eSr + f * DD + c4);
            es.x += cf * ev.x; es.y += cf * ev.y;
            es.z += cf * ev.z; es.w += cf * ev.w;
        }
        acc[i].x += es.x; acc[i].y += es.y;
        acc[i].z += es.z; acc[i].w += es.w;
    }

    // ---- rdeg + bf16 hi/lo split -> LDS (write at original row index) ----
    #pragma unroll
    for (int i = 0; i < 2; i++) {
        int r = rows[i];
        float rd = rdeg[n0 + r];
        float ax = acc[i].x * rd, ay = acc[i].y * rd, az = acc[i].z * rd, aw = acc[i].w * rd;
        unsigned short h0 = f2bf(ax), h1 = f2bf(ay), h2 = f2bf(az), h3 = f2bf(aw);
        unsigned short l0 = f2bf(ax - bf2f(h0));
        unsigned short l1 = f2bf(ay - bf2f(h1));
        unsigned short l2 = f2bf(az - bf2f(h2));
        unsigned short l3 = f2bf(aw - bf2f(h3));
        uint2 hv2, lv2;
        hv2.x = (unsigned)h0 | ((unsigned)h1 << 16);
        hv2.y = (unsigned)h2 | ((unsigned)h3 << 16);
        lv2.x = (unsigned)l0 | ((unsigned)l1 << 16);
        lv2.y = (unsigned)l2 | ((unsigned)l3 << 16);
        *(uint2*)(Xh + r * XS + c4) = hv2;
        *(uint2*)(Xl + r * XS + c4) = lv2;
    }
    __syncthreads();

    // ---- MFMA: 4 waves; one 16-row tile, wave w -> cols [w*32, w*32+32) ----
    int lane = tid & 63, w = tid >> 6;
    int m16 = lane & 15, quad = lane >> 4;
    int colBase = w << 5;

    floatx4 acc4[2];
    #pragma unroll
    for (int t = 0; t < 2; t++) acc4[t] = (floatx4){0.f, 0.f, 0.f, 0.f};

    #pragma unroll
    for (int kp = 0; kp < 4; kp++) {
        bf16x8 ah = *(const bf16x8*)(Xh + m16 * XS + kp * 32 + quad * 8);
        bf16x8 al = *(const bf16x8*)(Xl + m16 * XS + kp * 32 + quad * 8);
        #pragma unroll
        for (int t = 0; t < 2; t++) {
            int ncol = colBase + t * 16 + m16;
            bf16x8 bh = *(const bf16x8*)(Wht + (size_t)ncol * DD + kp * 32 + quad * 8);
            bf16x8 bl = *(const bf16x8*)(Wlt + (size_t)ncol * DD + kp * 32 + quad * 8);
            acc4[t] = __builtin_amdgcn_mfma_f32_16x16x32_bf16(ah, bh, acc4[t], 0, 0, 0);
            acc4[t] = __builtin_amdgcn_mfma_f32_16x16x32_bf16(ah, bl, acc4[t], 0, 0, 0);
            acc4[t] = __builtin_amdgcn_mfma_f32_16x16x32_bf16(al, bh, acc4[t], 0, 0, 0);
        }
    }
    __syncthreads();   // MFMA reads done -> Xh reusable as C buffer, eSr as red

    // ---- epilogue: bias, BN partials (fp32), pack bf16 C into LDS ----
    float* redS = eSr;
    float* redQ = eSr + DD;
    unsigned short* Cs = Xh;
    #pragma unroll
    for (int t = 0; t < 2; t++) {
        int col = colBase + t * 16 + m16;
        float bv = bias[col];
        float s = 0.f, q = 0.f;
        #pragma unroll
        for (int rr = 0; rr < 4; rr++) {
            float vv = acc4[t][rr] + bv;
            s += vv; q += vv * vv;
            Cs[(quad * 4 + rr) * XS + col] = f2bf(vv);
        }
        s += __shfl_xor(s, 16); q += __shfl_xor(q, 16);
        s += __shfl_xor(s, 32); q += __shfl_xor(q, 32);
        if (lane < 16) { redS[col] = s; redQ[col] = q; }
    }
    __syncthreads();

    // ---- coalesced bf16 C store (16 rows x 16 uint4 = 256 = one per thread) ----
    {
        int row = tid >> 4, q16 = tid & 15;
        uint4 v = *(const uint4*)(Cs + row * XS + q16 * 8);
        *(uint4*)(C + (size_t)(n0 + row) * DD + q16 * 8) = v;
    }
    if (tid < DD) {
        part[(size_t)blockIdx.x * 256 + tid] = redS[tid];
        part[(size_t)blockIdx.x * 256 + DD + tid] = redQ[tid];
    }
}

// ---------------- BN stat reduce + last-block finalize -> scale/shift ----------------
__global__ void k_stats(const float* __restrict__ part, float* __restrict__ acc,
                        int* __restrict__ cnt,
                        const float* __restrict__ gamma, const float* __restrict__ beta,
                        float* __restrict__ scale, float* __restrict__ shift) {
    int t = threadIdx.x;
    float s = 0.f;
    int base = blockIdx.x * (NBLK / SB);
    for (int i = 0; i < NBLK / SB; i++)
        s += part[(size_t)(base + i) * 256 + t];
    atomicAdd(&acc[t], s);
    __threadfence();
    __shared__ int lastS;
    __syncthreads();
    if (t == 0) lastS = (atomicAdd(cnt, 1) == SB - 1);
    __syncthreads();
    if (lastS && t < DD) {
        float Sv = atomicAdd(&acc[t], 0.0f);
        float Qv = atomicAdd(&acc[DD + t], 0.0f);
        float m = Sv / (float)NN;
        float v = Qv / (float)NN - m * m;
        float rs = rsqrtf(v + EPS);
        float sc = rs * gamma[t];
        scale[t] = sc;
        shift[t] = beta[t] - m * sc;
    }
}

// ---------------- last layer: act fused with graph-sum pooling (bf16 h) ----------------
__global__ void k_bnpool(const unsigned short* __restrict__ A, const int* __restrict__ n2g,
                         const float* __restrict__ scale, const float* __restrict__ shift,
                         float* __restrict__ gsum) {
    int tid = threadIdx.x;
    int stripe = tid >> 5, lane = tid & 31;
    int c4 = lane << 2;
    int n0 = blockIdx.x * PCH;
    float4 sc4 = *(const float4*)(scale + c4);
    float4 sh4 = *(const float4*)(shift + c4);
    float4 acc = {0.f, 0.f, 0.f, 0.f};
    int cur = n2g[n0 + stripe];
    for (int i = 0; i < PCH / 8; i++) {
        int n = n0 + i * 8 + stripe;
        int gg = n2g[n];
        if (gg != cur) {
            atomicAdd(&gsum[(size_t)cur * DD + c4 + 0], acc.x);
            atomicAdd(&gsum[(size_t)cur * DD + c4 + 1], acc.y);
            atomicAdd(&gsum[(size_t)cur * DD + c4 + 2], acc.z);
            atomicAdd(&gsum[(size_t)cur * DD + c4 + 3], acc.w);
            acc = (float4){0.f, 0.f, 0.f, 0.f};
            cur = gg;
        }
        uint2 v = *(const uint2*)(A + (size_t)n * DD + c4);
        float4 x = bf4_to_f4(v);
        acc.x += fmaxf(0.f, x.x * sc4.x + sh4.x);
        acc.y += fmaxf(0.f, x.y * sc4.y + sh4.y);
        acc.z += fmaxf(0.f, x.z * sc4.z + sh4.z);
        acc.w += fmaxf(0.f, x.w * sc4.w + sh4.w);
    }
    atomicAdd(&gsum[(size_t)cur * DD + c4 + 0], acc.x);
    atomicAdd(&gsum[(size_t)cur * DD + c4 + 1], acc.y);
    atomicAdd(&gsum[(size_t)cur * DD + c4 + 2], acc.z);
    atomicAdd(&gsum[(size_t)cur * DD + c4 + 3], acc.w);
}

// ---------------- final MLP ----------------
__global__ void k_mlp(const float* __restrict__ gsum, const float* __restrict__ gcnt,
                      const float* __restrict__ W1, const float* __restrict__ b1,
                      const float* __restrict__ W2, const float* __restrict__ b2,
                      float* __restrict__ out) {
    __shared__ float gs[DD], hs[DD];
    int gid = blockIdx.x, j = threadIdx.x;
    float inv = 1.0f / fmaxf(gcnt[gid], 1.0f);
    gs[j] = gsum[(size_t)gid * DD + j] * inv;
    __syncthreads();
    float a = b1[j];
    for (int k = 0; k < DD; k++) a += gs[k] * W1[k * DD + j];
    hs[j] = fmaxf(a, 0.f);
    __syncthreads();
    float o = b2[j];
    for (int k = 0; k < DD; k++) o += hs[k] * W2[k * DD + j];
    out[(size_t)gid * DD + j] = o;
}

extern "C" void kernel_launch(void* const* d_in, const int* in_sizes, int n_in,
                              void* d_out, int out_size, void* d_ws, size_t ws_size,
                              hipStream_t stream) {
    const int*   nfeat = (const int*)d_in[0];
    const int*   efeat = (const int*)d_in[1];
    const int*   src   = (const int*)d_in[2];
    const int*   dst   = (const int*)d_in[3];
    const int*   n2g   = (const int*)d_in[4];
    const float* aemb  = (const float*)d_in[5];
    const float* eemb  = (const float*)d_in[6];   // [L][5][128]
    const float* Wl    = (const float*)d_in[7];   // [L][128][128]
    const float* bl    = (const float*)d_in[8];   // [L][128]
    const float* gam   = (const float*)d_in[9];
    const float* bet   = (const float*)d_in[10];
    const float* W1    = (const float*)d_in[11];
    const float* b1    = (const float*)d_in[12];
    const float* W2    = (const float*)d_in[13];
    const float* b2    = (const float*)d_in[14];
    float* out = (float*)d_out;

    unsigned short* H0 = (unsigned short*)d_ws;          // NN*DD bf16
    unsigned short* H1 = H0 + (size_t)NN * DD;           // NN*DD bf16
    float* rdeg   = (float*)(H1 + (size_t)NN * DD);      // NN
    float* gsum   = rdeg + NN;                           // NG*DD
    float* gcnt   = gsum + (size_t)NG * DD;              // NG
    float* scaleA = gcnt + NG;                           // NL*DD
    float* shiftA = scaleA + NL * DD;                    // NL*DD
    float* accS   = shiftA + NL * DD;                    // NL*256
    int*   scnt   = (int*)(accS + NL * 256);             // 16
    float* part   = (float*)(scnt + 16);                 // NBLK*256 floats (12.8 MB)
    unsigned short* Wht = (unsigned short*)(part + (size_t)NBLK * 256);  // NL*DD*DD
    unsigned short* Wlt = Wht + (size_t)NL * DD * DD;
    int* off   = (int*)(Wlt + (size_t)NL * DD * DD);     // NN+1
    int* cur   = off + NN + 1;                           // NN (reused as hist after k_bucket)
    int* esrc  = cur + NN;                               // NE
    int* eft   = esrc + NE;                              // NE
    int* cnt   = eft + NE;                               // NN
    int* bsum  = cnt + NN;                               // NB_SCAN
    int* bpre  = bsum + NB_SCAN;                         // NB_SCAN
    int* bperm = bpre + NB_SCAN;                         // NBLK*16
    int* gmax  = bperm + (size_t)NBLK * BM;              // NBLK*8
    int* pent  = gmax + (size_t)NBLK * 8;                // NBLK*MAXD*BM (12.8 MB)
    int* pent0 = pent + (size_t)NBLK * MAXD * BM;        // NBLK*MAXD*BM (12.8 MB)
    int* hist  = cur;                                    // NN ints: cur is dead after k_bucket

    hipMemsetAsync(gsum, 0, (size_t)(NG * DD + NG) * sizeof(float), stream);
    hipMemsetAsync(accS, 0, (size_t)(NL * 256) * sizeof(float) + 16 * sizeof(int), stream);
    hipMemsetAsync(cnt, 0, (size_t)NN * sizeof(int), stream);

    k_setup1<<<(NE + 255) / 256, 256, 0, stream>>>(dst, cnt, n2g, gcnt, Wl, Wht, Wlt);
    k_scan1<<<NB_SCAN, 256, 0, stream>>>(cnt, bsum);
    k_scan2<<<1, 64, 0, stream>>>(bsum, bpre, off);
    k_scan3<<<NB_SCAN, 256, 0, stream>>>(cnt, bpre, off, cur, rdeg);
    k_bucket<<<(NE + 255) / 256, 256, 0, stream>>>(src, dst, efeat, cur, esrc, eft);
    k_pad<<<NBLK, 256, 0, stream>>>(off, esrc, eft, nfeat, pent, pent0, bperm, gmax, hist);

    unsigned short* hcur = H0;
    for (int l = 0; l < NL; l++) {
        const void* base = (l == 0) ? (const void*)aemb : (const void*)hcur;
        unsigned short* hnext = (l == 0) ? H0 : ((hcur == H0) ? H1 : H0);
        const int* psel = (l == 0) ? pent0 : pent;
        const float* scP = scaleA + (size_t)((l == 0) ? 0 : (l - 1)) * DD;
        const float* shP = shiftA + (size_t)((l == 0) ? 0 : (l - 1)) * DD;
        k_fused<<<NBLK, 256, 0, stream>>>(base, nfeat, (l == 0) ? 1 : 0,
                                          off, esrc, psel, bperm, gmax, hist,
                                          eemb + (size_t)l * BOND_V * DD, rdeg,
                                          scP, shP,
                                          Wht + (size_t)l * DD * DD,
                                          Wlt + (size_t)l * DD * DD,
                                          bl + (size_t)l * DD, hnext, part);
        k_stats<<<SB, 256, 0, stream>>>(part, accS + l * 256, scnt + l,
                                        gam + (size_t)l * DD, bet + (size_t)l * DD,
                                        scaleA + (size_t)l * DD, shiftA + (size_t)l * DD);
        hcur = hnext;
    }
    k_bnpool<<<NN / PCH, 256, 0, stream>>>(hcur, n2g,
                                           scaleA + (size_t)(NL - 1) * DD,
                                           shiftA + (size_t)(NL - 1) * DD, gsum);
    k_mlp<<<NG, DD, 0, stream>>>(gsum, gcnt, W1, b1, W2, b2, out);
}